// Round 16
// baseline (111.200 us; speedup 1.0000x reference)
//
#include <hip/hip_runtime.h>
#include <hip/hip_bf16.h>

#define N_NODES 262144
#define N_GRAPHS 256
#define DMODEL 256
#define LN2 0.6931471805599453094

typedef __attribute__((ext_vector_type(4))) float f32x4;
typedef __attribute__((ext_vector_type(8))) short short8;

__device__ __forceinline__ short bf(float x) {
    __hip_bfloat16 h = __float2bfloat16(x);
    return __builtin_bit_cast(short, h);
}

__device__ __forceinline__ short8 cvt8(f32x4 lo, f32x4 hi) {
    short8 a;
    a[0] = bf(lo[0]); a[1] = bf(lo[1]); a[2] = bf(lo[2]); a[3] = bf(lo[3]);
    a[4] = bf(hi[0]); a[5] = bf(hi[1]); a[6] = bf(hi[2]); a[7] = bf(hi[3]);
    return a;
}

// One bfrag ds_read feeds TWO MFMAs (row-frags m0/m1) -> halves LDS traffic.
__device__ __forceinline__ void mfma16(short8 a0, short8 a1, const char* bb,
                                       f32x4* accA, f32x4* accB) {
#pragma unroll
    for (int nt = 0; nt < 8; ++nt) {
        short8 bfrag = *reinterpret_cast<const short8*>(bb + nt * 1024);
        accA[nt] = __builtin_amdgcn_mfma_f32_16x16x32_bf16(a0, bfrag, accA[nt], 0, 0, 0);
        accB[nt] = __builtin_amdgcn_mfma_f32_16x16x32_bf16(a1, bfrag, accB[nt], 0, 0, 0);
    }
}

// l2 = log2(1 + 2^(log2e*min(r,64)));  softplus(r) = ln2 * l2 (exact)
__device__ __forceinline__ void elem(float r, int col, int bv,
                                     float& Sl2, float& Sl2p, float& Spr) {
    float t = fminf(r, 64.f) * 1.44269504f;
    float l2 = __log2f(1.f + exp2f(t));
    Sl2 += l2;
    float m = (col == bv) ? 1.f : 0.f;
    Sl2p = fmaf(m, l2, Sl2p);
    Spr = fmaf(m, r, Spr);
}

// R16 = R15 (512 blocks x 256 thr, 2 phase-drifted blocks/CU, 64KB LDS =
// one col-half of B, XCD-pair swizzle) + R10's mfma16 (1 ds_read feeds 2
// MFMAs -> per-CU LDS service 41us -> 20us). Wave: 32r x 128c, acc[2][8].
// 4 waves -> 128 rows/pass; 8 passes. Group-of-2-ks named-slot A pipeline.
__global__ __launch_bounds__(256, 1) void mvgrl_main(
    const float* __restrict__ l_enc, const float* __restrict__ g_enc,
    const int* __restrict__ batch, double* __restrict__ partials) {
    extern __shared__ char lds_raw[];  // 64KB: half of B in fragment order

    const int tid = threadIdx.x;
    const int lane = tid & 63;
    const int wave = tid >> 6;   // 0..3 = row stripe (32 rows each)
    const int bid = blockIdx.x;

    const int rg = (bid >> 4) * 8 + (bid & 7);  // row group 0..255
    const int chalf = (bid >> 3) & 1;           // column half
    const int row_blk = rg * 1024;
    const int kofs = (lane >> 4) * 8;

    // ---- pass-0 A preloads (warm pipeline): ks0/ks1 x m0/m1 ----
    f32x4 se0l, se0h, se1l, se1h, so0l, so0h, so1l, so1h;
    const float* arow = l_enc +
        (size_t)(row_blk + wave * 32 + (lane & 15)) * DMODEL + kofs;
    const float* am1 = arow + 16 * DMODEL;
    se0l = *reinterpret_cast<const f32x4*>(arow + 0);
    se0h = *reinterpret_cast<const f32x4*>(arow + 4);
    se1l = *reinterpret_cast<const f32x4*>(am1 + 0);
    se1h = *reinterpret_cast<const f32x4*>(am1 + 4);
    so0l = *reinterpret_cast<const f32x4*>(arow + 32);
    so0h = *reinterpret_cast<const f32x4*>(arow + 36);
    so1l = *reinterpret_cast<const f32x4*>(am1 + 32);
    so1h = *reinterpret_cast<const f32x4*>(am1 + 36);

    // ---- in-block B pack: our 128 cols of g_enc -> LDS fragment order ----
    // chunk c = ks*8 + nt (64 chunks, 1KB); within chunk lane*16B.
    {
        short8* lb = reinterpret_cast<short8*>(lds_raw);
#pragma unroll 2
        for (int i = 0; i < 16; ++i) {
            int c = wave + i * 4;          // 0..63
            int nt = c & 7, ks = c >> 3;
            int g = chalf * 128 + nt * 16 + (lane & 15);
            int k = ks * 32 + (lane >> 4) * 8;
            const float* src = g_enc + g * DMODEL + k;
            f32x4 lo = *reinterpret_cast<const f32x4*>(src);
            f32x4 hi = *reinterpret_cast<const f32x4*>(src + 4);
            lb[c * 64 + lane] = cvt8(lo, hi);
        }
    }
    __syncthreads();
    // no further barriers until final reduction

    const char* ldsB = lds_raw + lane * 16;
    double dS0 = 0.0, dS1 = 0.0, dS2 = 0.0;

#pragma unroll 1
    for (int pass = 0; pass < 8; ++pass) {
        const int rowbase = row_blk + pass * 128 + wave * 32;
        const int rsub = (lane >> 4) * 4;
        int bvA0 = batch[rowbase + rsub + 0];
        int bvA1 = batch[rowbase + rsub + 1];
        int bvA2 = batch[rowbase + rsub + 2];
        int bvA3 = batch[rowbase + rsub + 3];
        int bvB0 = batch[rowbase + 16 + rsub + 0];
        int bvB1 = batch[rowbase + 16 + rsub + 1];
        int bvB2 = batch[rowbase + 16 + rsub + 2];
        int bvB3 = batch[rowbase + 16 + rsub + 3];

        const float* arow_next = l_enc +
            (size_t)(row_blk + ((pass + 1) & 7) * 128 + wave * 32 + (lane & 15)) *
                DMODEL + kofs;

        f32x4 accA[8], accB[8];
#pragma unroll
        for (int n = 0; n < 8; ++n) {
            accA[n] = (f32x4){0.f, 0.f, 0.f, 0.f};
            accB[n] = (f32x4){0.f, 0.f, 0.f, 0.f};
        }

#pragma unroll 1
        for (int g = 0; g < 4; ++g) {
            // group g consumes ks 2g,2g+1; refill with group g+1's pair
            // (g=3 -> next pass ks0/1).
            const float* srcE = (g < 3) ? (arow + (2 * g + 2) * 32) : arow_next;
            const float* srcEm1 = srcE + 16 * DMODEL;
            // even ks = 2g
            {
                short8 a0 = cvt8(se0l, se0h);
                short8 a1 = cvt8(se1l, se1h);
                se0l = *reinterpret_cast<const f32x4*>(srcE + 0);
                se0h = *reinterpret_cast<const f32x4*>(srcE + 4);
                se1l = *reinterpret_cast<const f32x4*>(srcEm1 + 0);
                se1h = *reinterpret_cast<const f32x4*>(srcEm1 + 4);
                mfma16(a0, a1, ldsB + (size_t)(2 * g) * 8192, accA, accB);
            }
            // odd ks = 2g+1
            {
                short8 a0 = cvt8(so0l, so0h);
                short8 a1 = cvt8(so1l, so1h);
                so0l = *reinterpret_cast<const f32x4*>(srcE + 32);
                so0h = *reinterpret_cast<const f32x4*>(srcE + 36);
                so1l = *reinterpret_cast<const f32x4*>(srcEm1 + 32);
                so1h = *reinterpret_cast<const f32x4*>(srcEm1 + 36);
                mfma16(a0, a1, ldsB + (size_t)(2 * g + 1) * 8192, accA, accB);
            }
        }
        arow = arow_next;

        // ---- lean epilogue (log2 units) ----
        // C/D: col = chalf*128 + nt*16 + (lane&15);
        //      rowA = rowbase + rsub + rg, rowB = rowA + 16
        float Sl2 = 0.f, Sl2p = 0.f, Spr = 0.f;
        const int colbase = chalf * 128 + (lane & 15);
#pragma unroll
        for (int nt = 0; nt < 8; ++nt) {
            const int col = colbase + nt * 16;
            f32x4 avA = accA[nt];
            f32x4 avB = accB[nt];
            elem(avA[0], col, bvA0, Sl2, Sl2p, Spr);
            elem(avA[1], col, bvA1, Sl2, Sl2p, Spr);
            elem(avA[2], col, bvA2, Sl2, Sl2p, Spr);
            elem(avA[3], col, bvA3, Sl2, Sl2p, Spr);
            elem(avB[0], col, bvB0, Sl2, Sl2p, Spr);
            elem(avB[1], col, bvB1, Sl2, Sl2p, Spr);
            elem(avB[2], col, bvB2, Sl2, Sl2p, Spr);
            elem(avB[3], col, bvB3, Sl2, Sl2p, Spr);
        }
        dS0 += (double)Sl2;
        dS1 += (double)Sl2p;
        dS2 += (double)Spr;
    }

    // ---- reduction: wave shuffle -> LDS -> block partial ----
#pragma unroll
    for (int off = 32; off; off >>= 1) {
        dS0 += __shfl_xor(dS0, off);
        dS1 += __shfl_xor(dS1, off);
        dS2 += __shfl_xor(dS2, off);
    }
    __syncthreads();  // everyone done reading B before LDS reuse
    double* red = reinterpret_cast<double*>(lds_raw);
    if (lane == 0) {
        red[wave * 3 + 0] = dS0;
        red[wave * 3 + 1] = dS1;
        red[wave * 3 + 2] = dS2;
    }
    __syncthreads();
    if (tid == 0) {
        double a = 0, b = 0, c = 0;
#pragma unroll
        for (int w = 0; w < 4; ++w) {
            a += red[w * 3 + 0];
            b += red[w * 3 + 1];
            c += red[w * 3 + 2];
        }
        partials[bid * 3 + 0] = a;   // sum log2(1+2^t) (all)
        partials[bid * 3 + 1] = b;   // sum log2(1+2^t) (pos)
        partials[bid * 3 + 2] = c;   // sum r           (pos)
    }
}

__global__ void finalize_kernel(const double* __restrict__ p,
                                float* __restrict__ out) {
    int t = threadIdx.x;  // 512 threads, one partial-triple each
    double a = p[t * 3 + 0], b = p[t * 3 + 1], c = p[t * 3 + 2];
#pragma unroll
    for (int off = 32; off; off >>= 1) {
        a += __shfl_xor(a, off);
        b += __shfl_xor(b, off);
        c += __shfl_xor(c, off);
    }
    __shared__ double red[24];
    int lane = t & 63, w = t >> 6;
    if (lane == 0) { red[w * 3] = a; red[w * 3 + 1] = b; red[w * 3 + 2] = c; }
    __syncthreads();
    if (t == 0) {
        double A = 0, B = 0, C = 0;
#pragma unroll
        for (int i = 0; i < 8; ++i) {
            A += red[i * 3]; B += red[i * 3 + 1]; C += red[i * 3 + 2];
        }
        const double NN = (double)N_NODES, GG = (double)N_GRAPHS;
        double Sall_q = LN2 * A - NN * GG * LN2;
        double Spq = LN2 * B - NN * LN2;
        double Spr = C;
        double neg = (Sall_q - Spq) / (NN * (GG - 1.0));
        double pos = (Spr - Spq) / NN;
        out[0] = (float)(neg - pos);
    }
}

extern "C" void kernel_launch(void* const* d_in, const int* in_sizes, int n_in,
                              void* d_out, int out_size, void* d_ws,
                              size_t ws_size, hipStream_t stream) {
    const float* l_enc = (const float*)d_in[0];
    const float* g_enc = (const float*)d_in[1];
    const int* batch = (const int*)d_in[2];
    float* out = (float*)d_out;

    double* partials = (double*)d_ws;   // 512*3 doubles

    (void)hipFuncSetAttribute(reinterpret_cast<const void*>(mvgrl_main),
                              hipFuncAttributeMaxDynamicSharedMemorySize, 65536);

    mvgrl_main<<<512, 256, 65536, stream>>>(l_enc, g_enc, batch, partials);
    finalize_kernel<<<1, 512, 0, stream>>>(partials, out);
}